// Round 6
// baseline (200.607 us; speedup 1.0000x reference)
//
#include <hip/hip_runtime.h>
#include <stdint.h>

typedef unsigned long long u64;
typedef unsigned int u32;
typedef int i32x4 __attribute__((ext_vector_type(4)));

constexpr int Bn = 32;    // batch
constexpr int Cn = 512;   // channels (in == out)
constexpr int Ln = 4096;  // length
constexpr int Wn = 8;     // 512 channels / 64 bits

// ============================ helpers ============================
__device__ __forceinline__ void gload_lds16(const void* g, void* l) {
    __builtin_amdgcn_global_load_lds(
        (const __attribute__((address_space(1))) u32*)g,
        (__attribute__((address_space(3))) u32*)l, 16, 0, 0);
}

// ===================== MFMA path: pack weights =====================
// grid: 512 (one per co), 64 threads. wq layout: [k][co][ci] i8.
__global__ __launch_bounds__(64) void pack_w_i8_kernel(const float* __restrict__ w,
                                                       char* __restrict__ wq,
                                                       float* __restrict__ sw,
                                                       float* __restrict__ zpad) {
    const int co = blockIdx.x, lane = threadIdx.x;
    if (co == 0) { zpad[lane] = 0.0f; zpad[64 + lane] = 0.0f; }  // 512B zero pad region
    const float* wrow = w + (size_t)co * Cn * 3;
    float asum = 0.0f;
    for (int wi = 0; wi < Wn; ++wi) {
        const int ci = wi * 64 + lane;
        const float v0 = wrow[ci * 3 + 0], v1 = wrow[ci * 3 + 1], v2 = wrow[ci * 3 + 2];
        asum += fabsf(v0) + fabsf(v1) + fabsf(v2);
        wq[(size_t)0 * Cn * Cn + (size_t)co * Cn + ci] = (v0 > 0.0f) ? 1 : -1;
        wq[(size_t)1 * Cn * Cn + (size_t)co * Cn + ci] = (v1 > 0.0f) ? 1 : -1;
        wq[(size_t)2 * Cn * Cn + (size_t)co * Cn + ci] = (v2 > 0.0f) ? 1 : -1;
    }
    for (int off = 32; off; off >>= 1) asum += __shfl_xor(asum, off, 64);
    if (lane == 0) sw[co] = asum * (1.0f / (float)(Cn * 3));
}

// ===================== MFMA path: pack x (transpose to [b][l][ci]) =====================
// grid: dim3(Ln/256=16, Cn/64=8, Bn=32), 256 threads
__global__ __launch_bounds__(256) void pack_x_i8_kernel(const float* __restrict__ x,
                                                        char* __restrict__ xs,
                                                        float* __restrict__ partial) {
    __shared__ __align__(16) char sm[256 * 80];   // [l_local][ci pitch 80]
    __shared__ float red[4];
    const int b = blockIdx.z, ciG = blockIdx.y;
    const int l0 = blockIdx.x * 256, tid = threadIdx.x;
    const int ci0 = ciG * 64;
    const float* xb = x + ((size_t)b * Cn + ci0) * Ln + l0 + tid;
    float asum = 0.0f;
    u32 word = 0;
#pragma unroll 8
    for (int c = 0; c < 64; ++c) {
        const float v = xb[(size_t)c * Ln];          // coalesced across lanes
        asum += fabsf(v);
        word |= (u32)((v > 0.0f) ? 0x01u : 0xFFu) << ((c & 3) * 8);
        if ((c & 3) == 3) { *(u32*)&sm[tid * 80 + (c >> 2) * 4] = word; word = 0; }
    }
    for (int off = 32; off; off >>= 1) asum += __shfl_xor(asum, off, 64);
    if ((tid & 63) == 0) red[tid >> 6] = asum;
    __syncthreads();
    if (tid == 0) partial[b * 128 + ciG * 16 + blockIdx.x] = red[0] + red[1] + red[2] + red[3];
#pragma unroll
    for (int p = 0; p < 4; ++p) {
        const int row = p * 64 + (tid >> 2), ch = tid & 3;
        const i32x4 v = *(const i32x4*)&sm[row * 80 + ch * 16];
        *(i32x4*)(xs + ((size_t)b * Ln + l0 + row) * Cn + ci0 + ch * 16) = v;
    }
}

// ===================== finalize per-sample scale =====================
__global__ __launch_bounds__(128) void finalize_sx_kernel(const float* __restrict__ partial,
                                                          float* __restrict__ sx) {
    const int b = blockIdx.x;
    float v = partial[b * 128 + threadIdx.x];
    for (int off = 32; off; off >>= 1) v += __shfl_xor(v, off, 64);
    __shared__ float red[2];
    if ((threadIdx.x & 63) == 0) red[threadIdx.x >> 6] = v;
    __syncthreads();
    if (threadIdx.x == 0) sx[b] = (red[0] + red[1]) * (1.0f / (float)((size_t)Cn * Ln));
}

// ===================== implicit-GEMM i8 MFMA conv =====================
// grid: 4096 blocks (XCD-swizzled over co_t(8) x lt(16) x b(32)), 256 threads (4 waves)
// block tile: 64 co x 256 l; per-wave 64co x 64l (m=4,n=4). BK=64 ci, 3 taps.
// LDS: dbuf x (A [3][64][64]=12288 + B [258][64]=16512) = 57600.
// Schedule: tap-phased (3 phases/kt, barrier-delimited) + counted vmcnt + setprio.
__global__ __launch_bounds__(256, 2) void xgemm_kernel(
    const char* __restrict__ xs, const char* __restrict__ wq,
    const float* __restrict__ sw, const float* __restrict__ sx,
    const float* __restrict__ zpadf, float* __restrict__ out) {
    __shared__ __align__(16) char lds[57600];
    const int tid = threadIdx.x;
    const int lane = tid & 63, wid = tid >> 6;
    const int wc = wid;                       // wave owns l-strip wid*64
    const int lm = lane & 15, kb = lane >> 4;

    // bijective XCD-aware decode: within an XCD, co_t iterates fastest (shares B rows)
    const int X = blockIdx.x;
    const int xcd = X & 7, k = X >> 3;
    const int co_t = k & 7;
    const int P = (k >> 3) * 8 + xcd;         // [0,512)
    const int lt = P & 15, b = P >> 4;
    const int c0 = co_t * 64, l0 = lt * 256;

    const char* zpad = (const char*)zpadf;

    // staging sources (ko added per K-step); chunk XOR-swizzled, LDS linear
    const char* srcA[3];
#pragma unroll
    for (int p = 0; p < 3; ++p) {
        const int c = p * 256 + tid;
        const int tap = c >> 8, r = (c >> 2) & 63, jj = (c & 3) ^ ((r >> 1) & 3);
        srcA[p] = wq + (size_t)tap * Cn * Cn + (size_t)(c0 + r) * Cn + jj * 16;
    }
    const char* srcB[4];
#pragma unroll
    for (int p = 0; p < 4; ++p) {
        const int c = p * 256 + tid;
        const int row = c >> 2, jj = (c & 3) ^ ((row >> 1) & 3);
        const int l = l0 - 1 + row;
        srcB[p] = (l >= 0 && l < Ln) ? xs + ((size_t)b * Ln + l) * Cn + jj * 16 : zpad;
    }
    const char* srcB4;
    {
        const int c = 1024 + (lane & 7);
        const int row = c >> 2, jj = (c & 3) ^ ((row >> 1) & 3);
        const int l = l0 - 1 + row;
        srcB4 = (l >= 0 && l < Ln) ? xs + ((size_t)b * Ln + l) * Cn + jj * 16 : zpad;
    }

    // fragment LDS offsets (swizzle matches staging)
    int aoff[4];
#pragma unroll
    for (int m = 0; m < 4; ++m) {
        const int cr = m * 16 + lm;
        aoff[m] = cr * 64 + ((kb ^ ((cr >> 1) & 3)) << 4);
    }
    int boff[4][3];
#pragma unroll
    for (int n = 0; n < 4; ++n)
#pragma unroll
        for (int tap = 0; tap < 3; ++tap) {
            const int rr = wc * 64 + n * 16 + lm + tap;   // tile row = l - (l0-1)
            boff[n][tap] = rr * 64 + ((kb ^ ((rr >> 1) & 3)) << 4);
        }

    i32x4 acc[4][4] = {};

    auto stage = [&](int kt, int tb) {
        char* base = (char*)lds + tb * 28800;
        const int ko = kt * 64;
#pragma unroll
        for (int p = 0; p < 3; ++p)
            gload_lds16(srcA[p] + ko, base + (p * 256 + tid) * 16);
        char* bb = base + 12288;
#pragma unroll
        for (int p = 0; p < 4; ++p)
            gload_lds16(srcB[p] + ko, bb + (p * 256 + tid) * 16);
        if (wid == 0) {                       // scalar branch: only wave 0 issues (count 8)
            if (lane < 8)
                gload_lds16(srcB4 + ko, bb + (1024 + lane) * 16);
        }
    };

    stage(0, 0);
#pragma unroll
    for (int kt = 0; kt < 8; ++kt) {
        const int buf = kt & 1;
        if (kt < 7) {
            stage(kt + 1, buf ^ 1);           // issue next-tile loads (stay in flight)
            asm volatile("" ::: "memory");
            // counted drain: waits PREV tile's loads (issued a full K-step ago),
            // leaves this tile's 7-8 in flight across all 3 phases.
            if (wid == 0) asm volatile("s_waitcnt vmcnt(8)" ::: "memory");
            else          asm volatile("s_waitcnt vmcnt(7)" ::: "memory");
        } else {
            asm volatile("s_waitcnt vmcnt(0)" ::: "memory");
        }
        __builtin_amdgcn_s_barrier();         // buf fully staged for all waves

        const char* A = (const char*)lds + buf * 28800;
        const char* Bt = A + 12288;
        // ---- 3 tap-phases, barrier-delimited (T3 role-split; T5 pays here) ----
#pragma unroll
        for (int tap = 0; tap < 3; ++tap) {
            i32x4 af[4], bf[4];
#pragma unroll
            for (int m = 0; m < 4; ++m) af[m] = *(const i32x4*)(A + tap * 4096 + aoff[m]);
#pragma unroll
            for (int n = 0; n < 4; ++n) bf[n] = *(const i32x4*)(Bt + boff[n][tap]);
            __builtin_amdgcn_s_setprio(1);
#pragma unroll
            for (int m = 0; m < 4; ++m)
#pragma unroll
                for (int n = 0; n < 4; ++n)
                    acc[m][n] = __builtin_amdgcn_mfma_i32_16x16x64_i8(af[m], bf[n], acc[m][n], 0, 0, 0);
            __builtin_amdgcn_s_setprio(0);
            __builtin_amdgcn_s_barrier();     // phase boundary (last one guards buf reuse)
        }
    }

    // epilogue: scale + store. D: col=lane&15 (l), row=(lane>>4)*4+reg (co)
    const float sxb = sx[b];
#pragma unroll
    for (int m = 0; m < 4; ++m) {
        const int cob = c0 + m * 16 + kb * 4;
        const float4 swv = *(const float4*)(sw + cob);
        const float s0 = sxb * swv.x, s1 = sxb * swv.y, s2 = sxb * swv.z, s3 = sxb * swv.w;
#pragma unroll
        for (int n = 0; n < 4; ++n) {
            const int l = l0 + wc * 64 + n * 16 + lm;
            float* po = out + ((size_t)b * Cn + cob) * Ln + l;
            po[0]              = (float)acc[m][n][0] * s0;
            po[(size_t)Ln]     = (float)acc[m][n][1] * s1;
            po[(size_t)2 * Ln] = (float)acc[m][n][2] * s2;
            po[(size_t)3 * Ln] = (float)acc[m][n][3] * s3;
        }
    }
}

// ===================== fallback popcount path (round-1, passing) =====================
__global__ __launch_bounds__(64) void pack_w_kernel(const float* __restrict__ w,
                                                    u64* __restrict__ wp,
                                                    float* __restrict__ sw) {
    const int co = blockIdx.x;
    const int lane = threadIdx.x;
    const float* wrow = w + (size_t)co * Cn * 3;
    float asum = 0.0f;
    for (int wi = 0; wi < Wn; ++wi) {
        const int ci = wi * 64 + lane;
#pragma unroll
        for (int k = 0; k < 3; ++k) {
            const float v = wrow[ci * 3 + k];
            asum += fabsf(v);
            const u64 m = __ballot(v > 0.0f);
            if (lane == 0) wp[(co * 3 + k) * Wn + wi] = m;
        }
    }
    for (int off = 32; off; off >>= 1) asum += __shfl_xor(asum, off, 64);
    if (lane == 0) sw[co] = asum * (1.0f / (float)(Cn * 3));
}

__global__ __launch_bounds__(256) void pack_x_kernel(const float* __restrict__ x,
                                                     u64* __restrict__ xp,
                                                     float* __restrict__ partial) {
    const int b = blockIdx.z, wi = blockIdx.y;
    const int l = blockIdx.x * 256 + threadIdx.x;
    const float* xb = x + ((size_t)b * Cn + wi * 64) * Ln + l;
    u64 word = 0;
    float asum = 0.0f;
#pragma unroll 8
    for (int c = 0; c < 64; ++c) {
        const float v = xb[(size_t)c * Ln];
        asum += fabsf(v);
        word |= (u64)(v > 0.0f) << c;
    }
    xp[((size_t)b * Wn + wi) * Ln + l] = word;
    for (int off = 32; off; off >>= 1) asum += __shfl_xor(asum, off, 64);
    __shared__ float red[4];
    const int wave = threadIdx.x >> 6, lane = threadIdx.x & 63;
    if (lane == 0) red[wave] = asum;
    __syncthreads();
    if (threadIdx.x == 0)
        partial[b * 128 + wi * 16 + blockIdx.x] = red[0] + red[1] + red[2] + red[3];
}

__global__ __launch_bounds__(256) void conv_kernel(const u64* __restrict__ xp,
                                                   const u64* __restrict__ wp,
                                                   const float* __restrict__ sw,
                                                   const float* __restrict__ sx,
                                                   float* __restrict__ out) {
    __shared__ u64 wq[64 * 24];
    __shared__ float sws[64];
    const int b = blockIdx.z;
    const int c0 = blockIdx.y * 64;
    const int l0 = blockIdx.x * 64;
    for (int i = threadIdx.x; i < 64 * 24; i += 256) wq[i] = wp[(size_t)c0 * 24 + i];
    if (threadIdx.x < 64) sws[threadIdx.x] = sw[c0 + threadIdx.x];
    __syncthreads();
    const int lane = threadIdx.x & 63;
    const int wv = threadIdx.x >> 6;
    const int l = l0 + lane;
    const bool v0 = (l >= 1);
    const bool v2 = (l < Ln - 1);
    const int lmi = v0 ? l - 1 : l;
    const int lp = v2 ? l + 1 : l;
    const u64* xpb = xp + (size_t)b * Wn * Ln;
    u64 xq0[8], xq1[8], xq2[8];
#pragma unroll
    for (int wi = 0; wi < 8; ++wi) {
        const u64* p = xpb + (size_t)wi * Ln;
        xq0[wi] = p[lmi]; xq1[wi] = p[l]; xq2[wi] = p[lp];
    }
    const float sxb = sx[b];
    const size_t obase = ((size_t)b * Cn + c0 + wv * 16) * Ln + l;
#pragma unroll 2
    for (int ci = 0; ci < 16; ++ci) {
        const int col = wv * 16 + ci;
        const u64* wr = &wq[col * 24];
        int n0 = 0, n1 = 0, n2 = 0;
#pragma unroll
        for (int wi = 0; wi < 8; ++wi) {
            n0 += __popcll(xq0[wi] ^ wr[0 * 8 + wi]);
            n1 += __popcll(xq1[wi] ^ wr[1 * 8 + wi]);
            n2 += __popcll(xq2[wi] ^ wr[2 * 8 + wi]);
        }
        int s = 512 - 2 * n1;
        s += v0 ? (512 - 2 * n0) : 0;
        s += v2 ? (512 - 2 * n2) : 0;
        out[obase + (size_t)ci * Ln] = sxb * sws[col] * (float)s;
    }
}

// ============================ launch ============================
extern "C" void kernel_launch(void* const* d_in, const int* in_sizes, int n_in,
                              void* d_out, int out_size, void* d_ws, size_t ws_size,
                              hipStream_t stream) {
    const float* x = (const float*)d_in[0];   // [32, 512, 4096] f32
    const float* w = (const float*)d_in[1];   // [512, 512, 3]  f32
    float* out = (float*)d_out;               // [32, 512, 4096] f32
    char* ws = (char*)d_ws;

    const size_t NEED = 67914368;  // xs 67108864 + wq 786432 + zpad 512 + sw 2048 + sx 128 + partial 16384
    if (ws_size >= NEED) {
        char* xs = ws;                                  // [b][l][ci] i8
        char* wq = ws + 67108864;                       // [k][co][ci] i8
        float* zpad = (float*)(ws + 67895296);          // 512 B zeros
        float* sw = (float*)(ws + 67895808);
        float* sx = (float*)(ws + 67897856);
        float* partial = (float*)(ws + 67897984);

        pack_w_i8_kernel<<<dim3(Cn), dim3(64), 0, stream>>>(w, wq, sw, zpad);
        pack_x_i8_kernel<<<dim3(Ln / 256, Cn / 64, Bn), dim3(256), 0, stream>>>(x, xs, partial);
        finalize_sx_kernel<<<dim3(Bn), dim3(128), 0, stream>>>(partial, sx);
        xgemm_kernel<<<dim3(4096), dim3(256), 0, stream>>>(xs, wq, sw, sx, zpad, out);
    } else {
        const size_t xp_bytes = (size_t)Bn * Wn * Ln * sizeof(u64);
        const size_t wp_bytes = (size_t)Cn * 3 * Wn * sizeof(u64);
        u64* xp = (u64*)ws;
        u64* wp = (u64*)(ws + xp_bytes);
        float* sw = (float*)(ws + xp_bytes + wp_bytes);
        float* partial = sw + Cn;
        float* sx = partial + Bn * 128;

        pack_w_kernel<<<dim3(Cn), dim3(64), 0, stream>>>(w, wp, sw);
        pack_x_kernel<<<dim3(Ln / 256, Wn, Bn), dim3(256), 0, stream>>>(x, xp, partial);
        finalize_sx_kernel<<<dim3(Bn), dim3(128), 0, stream>>>(partial, sx);
        conv_kernel<<<dim3(Ln / 64, Cn / 64, Bn), dim3(256), 0, stream>>>(xp, wp, sw, sx, out);
    }
}

// Round 8
// 166.030 us; speedup vs baseline: 1.2083x; 1.2083x over previous
//
#include <hip/hip_runtime.h>
#include <stdint.h>

typedef unsigned long long u64;
typedef unsigned int u32;
typedef int i32x4 __attribute__((ext_vector_type(4)));
typedef int i32x8 __attribute__((ext_vector_type(8)));
typedef float f32x16 __attribute__((ext_vector_type(16)));

constexpr int Bn = 32;    // batch
constexpr int Cn = 512;   // channels (in == out)
constexpr int Ln = 4096;  // length
constexpr int Wn = 8;

// ============================ helpers ============================
__device__ __forceinline__ void gload_lds16(const void* g, void* l) {
    __builtin_amdgcn_global_load_lds(
        (const __attribute__((address_space(1))) u32*)g,
        (__attribute__((address_space(3))) u32*)l, 16, 0, 0);
}

// ===================== FP4 path: pack weights =====================
// grid: 512 (one per co), 64 threads. wq4: [tap][co][ci/2] nibbles (u32-indexed).
// fp4 e2m1: +1.0 = 0x2, -1.0 = 0xA, 0 = 0x0.  (0x4/0xC are +-2.0 -- R7 bug!)
__global__ __launch_bounds__(64) void pack_w_fp4_kernel(const float* __restrict__ w,
                                                        u32* __restrict__ wq4,
                                                        float* __restrict__ sw,
                                                        float* __restrict__ zpad) {
    const int co = blockIdx.x, lane = threadIdx.x;
    if (co == 0) { zpad[lane] = 0.0f; zpad[64 + lane] = 0.0f; }  // 512 B zeros
    const float* wrow = w + (size_t)co * Cn * 3;
    float asum = 0.0f;
#pragma unroll
    for (int tap = 0; tap < 3; ++tap) {
        u32 word = 0;
#pragma unroll
        for (int j = 0; j < 8; ++j) {                 // ci = lane*8 + j
            const float v = wrow[(lane * 8 + j) * 3 + tap];
            asum += fabsf(v);
            word |= ((v > 0.0f) ? 0x2u : 0xAu) << (j * 4);
        }
        wq4[(size_t)tap * Cn * 64 + co * 64 + lane] = word;
    }
    for (int off = 32; off; off >>= 1) asum += __shfl_xor(asum, off, 64);
    if (lane == 0) sw[co] = asum * (1.0f / (float)(Cn * 3));
}

// ===================== FP4 path: pack x → [b][l][ci/2] nibbles =====================
// grid: dim3(Ln/64=64, Bn=32), 256 threads. Each block: 64 l x all 512 ci.
__global__ __launch_bounds__(256) void pack_x_fp4_kernel(const float* __restrict__ x,
                                                         char* __restrict__ xs4,
                                                         float* __restrict__ partial) {
    __shared__ u32 sm[64 * 65];    // [l_local][64 data dwords + 1 pad]
    __shared__ float red[4];
    const int b = blockIdx.y, l0 = blockIdx.x * 64;
    const int t = threadIdx.x;
    const int lrow = t & 63, cseg = t >> 6;           // cseg = wave id (128 ci each)
    const float* xb = x + ((size_t)b * Cn + cseg * 128) * Ln + l0 + lrow;
    float asum = 0.0f;
#pragma unroll 2
    for (int j = 0; j < 16; ++j) {
        u32 word = 0;
#pragma unroll
        for (int c = 0; c < 8; ++c) {
            const float v = xb[(size_t)(j * 8 + c) * Ln];   // coalesced across lanes
            asum += fabsf(v);
            word |= ((v > 0.0f) ? 0x2u : 0xAu) << (c * 4);
        }
        sm[lrow * 65 + cseg * 16 + j] = word;
    }
    for (int off = 32; off; off >>= 1) asum += __shfl_xor(asum, off, 64);
    if ((t & 63) == 0) red[t >> 6] = asum;
    __syncthreads();
    if (t == 0) partial[b * 64 + blockIdx.x] = red[0] + red[1] + red[2] + red[3];
    // readout: 64 rows x 256 B = 1024 x 16B slots; 4 per thread, coalesced 1KB/wave
#pragma unroll
    for (int j = 0; j < 4; ++j) {
        const int s = j * 256 + t;
        const int row = s >> 4, ch = s & 15;
        i32x4 v;
#pragma unroll
        for (int q = 0; q < 4; ++q) v[q] = (int)sm[row * 65 + ch * 4 + q];
        *(i32x4*)(xs4 + ((size_t)b * Ln + l0 + row) * 256 + ch * 16) = v;
    }
}

// ===================== finalize per-sample scale (64 partials/b) =====================
__global__ __launch_bounds__(64) void finalize_sx64_kernel(const float* __restrict__ partial,
                                                           float* __restrict__ sx) {
    const int b = blockIdx.x, lane = threadIdx.x;
    float v = partial[b * 64 + lane];
    for (int off = 32; off; off >>= 1) v += __shfl_xor(v, off, 64);
    if (lane == 0) sx[b] = v * (1.0f / (float)((size_t)Cn * Ln));
}

// ===================== implicit-GEMM MX-FP4 MFMA conv =====================
// grid: 4096 blocks (XCD-swizzled over co_t(8) x lt(16) x b(32)), 256 threads (4 waves)
// block tile: 64 co x 256 l; per-wave 64co x 64l as 2x2 of 32x32, BK=64 ci, 3 taps.
// LDS: dbuf x (A [3][64][32B]=6144 + B [258][32B]=8256) = 28800. Rows are 32 B ->
// fragment ds_read_b128 are dense (lane<32: +0, lane>=32: +16) -> conflict-free, no swizzle.
__global__ __launch_bounds__(256, 3) void xgemm_fp4_kernel(
    const char* __restrict__ xs4, const char* __restrict__ wq4,
    const float* __restrict__ sw, const float* __restrict__ sx,
    const float* __restrict__ zpadf, float* __restrict__ out) {
    __shared__ __align__(16) char lds[28800];
    const int tid = threadIdx.x;
    const int lane = tid & 63, wid = tid >> 6;
    const int wc = wid;                       // wave owns l-strip wid*64
    const int cl = lane & 31, kh = lane >> 5; // MFMA col/row lane, k-half

    // bijective XCD-aware decode: within an XCD, co_t iterates fastest (shares B tile)
    const int X = blockIdx.x;
    const int xcd = X & 7, k = X >> 3;
    const int co_t = k & 7;
    const int P = (k >> 3) * 8 + xcd;         // [0,512)
    const int lt = P & 15, b = P >> 4;
    const int c0 = co_t * 64, l0 = lt * 256;

    const char* zpad = (const char*)zpadf;
    const char* wqb = wq4;

    // staging sources (ko = kt*32 bytes added per K-step); LDS linear.
    // A slots (384): s = tap*128 + co*2 + h  -> 16B at wq4[tap][c0+co][] + h*16
    const char* sA0;  // slot tid
    const char* sA1;  // slot 256+tid (tid<128), tap 2
    {
        int s = tid;
        sA0 = wqb + (size_t)(s >> 7) * Cn * 256 + (size_t)(c0 + ((s >> 1) & 63)) * 256 + (s & 1) * 16;
        s = 256 + (tid & 127);
        sA1 = wqb + (size_t)(s >> 7) * Cn * 256 + (size_t)(c0 + ((s >> 1) & 63)) * 256 + (s & 1) * 16;
    }
    // B slots (516): s = row*2 + h, row = l - (l0-1)
    const char* sB0;
    const char* sB1;
    const char* sB2;
    {
        int s = tid;
        int row = s >> 1, l = l0 - 1 + row;
        sB0 = (l >= 0 && l < Ln) ? xs4 + ((size_t)b * Ln + l) * 256 + (s & 1) * 16 : zpad;
        s = 256 + tid; row = s >> 1; l = l0 - 1 + row;
        sB1 = (l >= 0 && l < Ln) ? xs4 + ((size_t)b * Ln + l) * 256 + (s & 1) * 16 : zpad;
        s = 512 + (lane & 3); row = s >> 1; l = l0 - 1 + row;
        sB2 = (l >= 0 && l < Ln) ? xs4 + ((size_t)b * Ln + l) * 256 + (s & 1) * 16 : zpad;
    }

    // fragment LDS offsets: A row = m*32+cl (co), byte kh*16; B row = wc*64+n*32+cl+tap
    int aoff[2];
#pragma unroll
    for (int m = 0; m < 2; ++m) aoff[m] = (m * 32 + cl) * 32 + kh * 16;
    int boff[2][3];
#pragma unroll
    for (int n = 0; n < 2; ++n)
#pragma unroll
        for (int tap = 0; tap < 3; ++tap)
            boff[n][tap] = (wc * 64 + n * 32 + cl + tap) * 32 + kh * 16;

    f32x16 acc[2][2] = {};

    auto stage = [&](int kt, int tb) {
        char* base = (char*)lds + tb * 14400;
        const int ko = kt * 32;
        gload_lds16(sA0 + ko, base + tid * 16);
        if (wid < 2) gload_lds16(sA1 + ko, base + (256 + tid) * 16);   // tid<128
        char* bb = base + 6144;
        gload_lds16(sB0 + ko, bb + tid * 16);
        gload_lds16(sB1 + ko, bb + (256 + tid) * 16);
        if (wid == 0) {
            if (lane < 4) gload_lds16(sB2 + ko, bb + (512 + lane) * 16);
        }
    };
    // per-wave in-flight load counts: w0=5, w1=4, w2/3=3

    auto compute = [&](int tb) {
        const char* A = (const char*)lds + tb * 14400;
        const char* Bt = A + 6144;
#pragma unroll
        for (int tap = 0; tap < 3; ++tap) {
            i32x8 av[2], bv[2];
#pragma unroll
            for (int m = 0; m < 2; ++m) {
                const i32x4 t4 = *(const i32x4*)(A + tap * 2048 + aoff[m]);
                av[m] = i32x8{t4[0], t4[1], t4[2], t4[3], 0, 0, 0, 0};
            }
#pragma unroll
            for (int n = 0; n < 2; ++n) {
                const i32x4 t4 = *(const i32x4*)(Bt + boff[n][tap]);
                bv[n] = i32x8{t4[0], t4[1], t4[2], t4[3], 0, 0, 0, 0};
            }
            __builtin_amdgcn_s_setprio(1);
#pragma unroll
            for (int m = 0; m < 2; ++m)
#pragma unroll
                for (int n = 0; n < 2; ++n)
                    acc[m][n] = __builtin_amdgcn_mfma_scale_f32_32x32x64_f8f6f4(
                        av[m], bv[n], acc[m][n], 4 /*fp4 A*/, 4 /*fp4 B*/,
                        0, 0x7F7F7F7F, 0, 0x7F7F7F7F);   // e8m0 scales = 1.0
            __builtin_amdgcn_s_setprio(0);
        }
    };

    stage(0, 0);
#pragma unroll
    for (int kt = 0; kt < 8; ++kt) {
        const int buf = kt & 1;
        if (kt < 7) {
            stage(kt + 1, buf ^ 1);           // next-tile loads stay in flight
            asm volatile("" ::: "memory");
            if (wid == 0)      asm volatile("s_waitcnt vmcnt(5)" ::: "memory");
            else if (wid == 1) asm volatile("s_waitcnt vmcnt(4)" ::: "memory");
            else               asm volatile("s_waitcnt vmcnt(3)" ::: "memory");
        } else {
            asm volatile("s_waitcnt vmcnt(0)" ::: "memory");
        }
        __builtin_amdgcn_s_barrier();         // buf fully staged for all waves
        compute(buf);
        asm volatile("" ::: "memory");
        __builtin_amdgcn_s_barrier();         // all waves done reading buf
    }

    // epilogue. 32x32 D: col=lane&31 (l), row=(reg&3)+8*(reg>>2)+4*(lane>>5) (co)
    const float sxb = sx[b];
#pragma unroll
    for (int m = 0; m < 2; ++m)
#pragma unroll
        for (int n = 0; n < 2; ++n) {
            const int l = l0 + wc * 64 + n * 32 + cl;
#pragma unroll
            for (int g = 0; g < 4; ++g) {
                const int cob = c0 + m * 32 + g * 8 + kh * 4;
                const float4 swv = *(const float4*)(sw + cob);
                float* po = out + ((size_t)b * Cn + cob) * Ln + l;
                po[0]              = acc[m][n][g * 4 + 0] * (sxb * swv.x);
                po[(size_t)Ln]     = acc[m][n][g * 4 + 1] * (sxb * swv.y);
                po[(size_t)2 * Ln] = acc[m][n][g * 4 + 2] * (sxb * swv.z);
                po[(size_t)3 * Ln] = acc[m][n][g * 4 + 3] * (sxb * swv.w);
            }
        }
}

// ===================== fallback popcount path (round-1, passing) =====================
__global__ __launch_bounds__(64) void pack_w_kernel(const float* __restrict__ w,
                                                    u64* __restrict__ wp,
                                                    float* __restrict__ sw) {
    const int co = blockIdx.x;
    const int lane = threadIdx.x;
    const float* wrow = w + (size_t)co * Cn * 3;
    float asum = 0.0f;
    for (int wi = 0; wi < Wn; ++wi) {
        const int ci = wi * 64 + lane;
#pragma unroll
        for (int k = 0; k < 3; ++k) {
            const float v = wrow[ci * 3 + k];
            asum += fabsf(v);
            const u64 m = __ballot(v > 0.0f);
            if (lane == 0) wp[(co * 3 + k) * Wn + wi] = m;
        }
    }
    for (int off = 32; off; off >>= 1) asum += __shfl_xor(asum, off, 64);
    if (lane == 0) sw[co] = asum * (1.0f / (float)(Cn * 3));
}

__global__ __launch_bounds__(256) void pack_x_kernel(const float* __restrict__ x,
                                                     u64* __restrict__ xp,
                                                     float* __restrict__ partial) {
    const int b = blockIdx.z, wi = blockIdx.y;
    const int l = blockIdx.x * 256 + threadIdx.x;
    const float* xb = x + ((size_t)b * Cn + wi * 64) * Ln + l;
    u64 word = 0;
    float asum = 0.0f;
#pragma unroll 8
    for (int c = 0; c < 64; ++c) {
        const float v = xb[(size_t)c * Ln];
        asum += fabsf(v);
        word |= (u64)(v > 0.0f) << c;
    }
    xp[((size_t)b * Wn + wi) * Ln + l] = word;
    for (int off = 32; off; off >>= 1) asum += __shfl_xor(asum, off, 64);
    __shared__ float red[4];
    const int wave = threadIdx.x >> 6, lane = threadIdx.x & 63;
    if (lane == 0) red[wave] = asum;
    __syncthreads();
    if (threadIdx.x == 0)
        partial[b * 128 + wi * 16 + blockIdx.x] = red[0] + red[1] + red[2] + red[3];
}

__global__ __launch_bounds__(128) void finalize_sx_kernel(const float* __restrict__ partial,
                                                          float* __restrict__ sx) {
    const int b = blockIdx.x;
    float v = partial[b * 128 + threadIdx.x];
    for (int off = 32; off; off >>= 1) v += __shfl_xor(v, off, 64);
    __shared__ float red[2];
    if ((threadIdx.x & 63) == 0) red[threadIdx.x >> 6] = v;
    __syncthreads();
    if (threadIdx.x == 0) sx[b] = (red[0] + red[1]) * (1.0f / (float)((size_t)Cn * Ln));
}

__global__ __launch_bounds__(256) void conv_kernel(const u64* __restrict__ xp,
                                                   const u64* __restrict__ wp,
                                                   const float* __restrict__ sw,
                                                   const float* __restrict__ sx,
                                                   float* __restrict__ out) {
    __shared__ u64 wq[64 * 24];
    __shared__ float sws[64];
    const int b = blockIdx.z;
    const int c0 = blockIdx.y * 64;
    const int l0 = blockIdx.x * 64;
    for (int i = threadIdx.x; i < 64 * 24; i += 256) wq[i] = wp[(size_t)c0 * 24 + i];
    if (threadIdx.x < 64) sws[threadIdx.x] = sw[c0 + threadIdx.x];
    __syncthreads();
    const int lane = threadIdx.x & 63;
    const int wv = threadIdx.x >> 6;
    const int l = l0 + lane;
    const bool v0 = (l >= 1);
    const bool v2 = (l < Ln - 1);
    const int lmi = v0 ? l - 1 : l;
    const int lp = v2 ? l + 1 : l;
    const u64* xpb = xp + (size_t)b * Wn * Ln;
    u64 xq0[8], xq1[8], xq2[8];
#pragma unroll
    for (int wi = 0; wi < 8; ++wi) {
        const u64* p = xpb + (size_t)wi * Ln;
        xq0[wi] = p[lmi]; xq1[wi] = p[l]; xq2[wi] = p[lp];
    }
    const float sxb = sx[b];
    const size_t obase = ((size_t)b * Cn + c0 + wv * 16) * Ln + l;
#pragma unroll 2
    for (int ci = 0; ci < 16; ++ci) {
        const int col = wv * 16 + ci;
        const u64* wr = &wq[col * 24];
        int n0 = 0, n1 = 0, n2 = 0;
#pragma unroll
        for (int wi = 0; wi < 8; ++wi) {
            n0 += __popcll(xq0[wi] ^ wr[0 * 8 + wi]);
            n1 += __popcll(xq1[wi] ^ wr[1 * 8 + wi]);
            n2 += __popcll(xq2[wi] ^ wr[2 * 8 + wi]);
        }
        int s = 512 - 2 * n1;
        s += v0 ? (512 - 2 * n0) : 0;
        s += v2 ? (512 - 2 * n2) : 0;
        out[obase + (size_t)ci * Ln] = sxb * sws[col] * (float)s;
    }
}

// ============================ launch ============================
extern "C" void kernel_launch(void* const* d_in, const int* in_sizes, int n_in,
                              void* d_out, int out_size, void* d_ws, size_t ws_size,
                              hipStream_t stream) {
    const float* x = (const float*)d_in[0];   // [32, 512, 4096] f32
    const float* w = (const float*)d_in[1];   // [512, 512, 3]  f32
    float* out = (float*)d_out;               // [32, 512, 4096] f32
    char* ws = (char*)d_ws;

    // fp4 path workspace: xs4 33554432 | wq4 393216 | zpad 512 | sw 2048 | sx 128 | partial 8192
    const size_t NEED = 33958528;
    if (ws_size >= NEED) {
        char* xs4 = ws;                              // [b][l][ci/2] fp4
        u32* wq4 = (u32*)(ws + 33554432);            // [tap][co][ci/2] fp4
        float* zpad = (float*)(ws + 33947648);       // 512 B zeros
        float* sw = (float*)(ws + 33948160);
        float* sx = (float*)(ws + 33950208);
        float* partial = (float*)(ws + 33950336);

        pack_w_fp4_kernel<<<dim3(Cn), dim3(64), 0, stream>>>(w, wq4, sw, zpad);
        pack_x_fp4_kernel<<<dim3(Ln / 64, Bn), dim3(256), 0, stream>>>(x, xs4, partial);
        finalize_sx64_kernel<<<dim3(Bn), dim3(64), 0, stream>>>(partial, sx);
        xgemm_fp4_kernel<<<dim3(4096), dim3(256), 0, stream>>>(xs4, (const char*)wq4, sw, sx, zpad, out);
    } else {
        const size_t xp_bytes = (size_t)Bn * Wn * Ln * sizeof(u64);
        const size_t wp_bytes = (size_t)Cn * 3 * Wn * sizeof(u64);
        u64* xp = (u64*)ws;
        u64* wp = (u64*)(ws + xp_bytes);
        float* sw = (float*)(ws + xp_bytes + wp_bytes);
        float* partial = sw + Cn;
        float* sx = partial + Bn * 128;

        pack_w_kernel<<<dim3(Cn), dim3(64), 0, stream>>>(w, wp, sw);
        pack_x_kernel<<<dim3(Ln / 256, Wn, Bn), dim3(256), 0, stream>>>(x, xp, partial);
        finalize_sx_kernel<<<dim3(Bn), dim3(128), 0, stream>>>(partial, sx);
        conv_kernel<<<dim3(Ln / 64, Cn / 64, Bn), dim3(256), 0, stream>>>(xp, wp, sw, sx, out);
    }
}

// Round 10
// 141.364 us; speedup vs baseline: 1.4191x; 1.1745x over previous
//
#include <hip/hip_runtime.h>
#include <stdint.h>

typedef unsigned long long u64;
typedef unsigned int u32;
typedef int i32x4 __attribute__((ext_vector_type(4)));
typedef int i32x8 __attribute__((ext_vector_type(8)));
typedef float f32x4 __attribute__((ext_vector_type(4)));
typedef float f32x16 __attribute__((ext_vector_type(16)));

constexpr int Bn = 32;    // batch
constexpr int Cn = 512;   // channels (in == out)
constexpr int Ln = 4096;  // length
constexpr int Wn = 8;

// ============================ helpers ============================
__device__ __forceinline__ void gload_lds16(const void* g, void* l) {
    __builtin_amdgcn_global_load_lds(
        (const __attribute__((address_space(1))) u32*)g,
        (__attribute__((address_space(3))) u32*)l, 16, 0, 0);
}

// ===================== FP4 path: pack weights =====================
// grid: 512 (one per co), 64 threads. wq4: [tap][co][ci/2] nibbles (u32-indexed).
// fp4 e2m1: +1.0 = 0x2, -1.0 = 0xA, 0 = 0x0.
__global__ __launch_bounds__(64) void pack_w_fp4_kernel(const float* __restrict__ w,
                                                        u32* __restrict__ wq4,
                                                        float* __restrict__ sw,
                                                        float* __restrict__ zpad) {
    const int co = blockIdx.x, lane = threadIdx.x;
    if (co == 0) { zpad[lane] = 0.0f; zpad[64 + lane] = 0.0f; }  // 512 B zeros
    const float* wrow = w + (size_t)co * Cn * 3;
    float asum = 0.0f;
#pragma unroll
    for (int tap = 0; tap < 3; ++tap) {
        u32 word = 0;
#pragma unroll
        for (int j = 0; j < 8; ++j) {                 // ci = lane*8 + j
            const float v = wrow[(lane * 8 + j) * 3 + tap];
            asum += fabsf(v);
            word |= ((v > 0.0f) ? 0x2u : 0xAu) << (j * 4);
        }
        wq4[(size_t)tap * Cn * 64 + co * 64 + lane] = word;
    }
    for (int off = 32; off; off >>= 1) asum += __shfl_xor(asum, off, 64);
    if (lane == 0) sw[co] = asum * (1.0f / (float)(Cn * 3));
}

// ===================== FP4 path: pack x → [b][l][ci/2] nibbles (float4 loads) ==========
// grid: dim3(Ln/64=64, Bn=32), 256 threads. Block: 64 l x 512 ci.
// thread: 4 consecutive l's ((t&15)*4) x 32 consecutive ci's ((t>>4)*32) -> f32x4 loads.
__global__ __launch_bounds__(256) void pack_x_fp4_kernel(const float* __restrict__ x,
                                                         char* __restrict__ xs4,
                                                         float* __restrict__ partial) {
    __shared__ u32 sm[64 * 65];    // [l_local][64 data dwords + 1 pad]
    __shared__ float red[4];
    const int b = blockIdx.y, l0 = blockIdx.x * 64;
    const int t = threadIdx.x;
    const int lr4 = (t & 15) * 4;                      // base l row (4 rows)
    const int cblk = (t >> 4) * 32;                    // 32 consecutive ci
    const float* xb = x + ((size_t)b * Cn + cblk) * Ln + l0 + lr4;
    float asum = 0.0f;
    u32 wd[4] = {0, 0, 0, 0};
#pragma unroll
    for (int j = 0; j < 32; ++j) {
        const f32x4 v = __builtin_nontemporal_load(
            reinterpret_cast<const f32x4*>(xb + (size_t)j * Ln));
        asum += fabsf(v[0]) + fabsf(v[1]) + fabsf(v[2]) + fabsf(v[3]);
        const int sh = (j & 7) * 4;
        wd[0] |= ((v[0] > 0.0f) ? 0x2u : 0xAu) << sh;
        wd[1] |= ((v[1] > 0.0f) ? 0x2u : 0xAu) << sh;
        wd[2] |= ((v[2] > 0.0f) ? 0x2u : 0xAu) << sh;
        wd[3] |= ((v[3] > 0.0f) ? 0x2u : 0xAu) << sh;
        if ((j & 7) == 7) {
            const int widx = (t >> 4) * 4 + (j >> 3);
#pragma unroll
            for (int q = 0; q < 4; ++q) { sm[(lr4 + q) * 65 + widx] = wd[q]; wd[q] = 0; }
        }
    }
    for (int off = 32; off; off >>= 1) asum += __shfl_xor(asum, off, 64);
    if ((t & 63) == 0) red[t >> 6] = asum;
    __syncthreads();
    if (t == 0) partial[b * 64 + blockIdx.x] = red[0] + red[1] + red[2] + red[3];
    // readout: 64 rows x 256 B = 1024 x 16B slots; 4 per thread, coalesced
#pragma unroll
    for (int j = 0; j < 4; ++j) {
        const int s = j * 256 + t;
        const int row = s >> 4, ch = s & 15;
        i32x4 v;
#pragma unroll
        for (int q = 0; q < 4; ++q) v[q] = (int)sm[row * 65 + ch * 4 + q];
        *(i32x4*)(xs4 + ((size_t)b * Ln + l0 + row) * 256 + ch * 16) = v;
    }
}

// ===================== implicit-GEMM MX-FP4 MFMA conv =====================
// grid: 4096 blocks (XCD-swizzled over co_t(8) x lt(16) x b(32)), 256 threads (4 waves)
// block tile: 64 co x 256 l; per-wave 64co x 64l as 2x2 of 32x32, BK=64 ci, 3 taps.
// LDS: 3 bufs x (A [3][64][32B]=6144 + B [258][32B]=8256) = 43200, depth-2 prefetch.
// sx computed in-kernel from partial sums (finalize kernel folded in).
__global__ __launch_bounds__(256, 3) void xgemm_fp4_kernel(
    const char* __restrict__ xs4, const char* __restrict__ wq4,
    const float* __restrict__ sw, const float* __restrict__ partial,
    const float* __restrict__ zpadf, float* __restrict__ out) {
    __shared__ __align__(16) char lds[43200];
    const int tid = threadIdx.x;
    const int lane = tid & 63, wid = tid >> 6;
    const int wc = wid;                       // wave owns l-strip wid*64
    const int cl = lane & 31, kh = lane >> 5; // MFMA col/row lane, k-half

    // bijective XCD-aware decode: within an XCD, co_t iterates fastest (shares B tile)
    const int X = blockIdx.x;
    const int xcd = X & 7, k = X >> 3;
    const int co_t = k & 7;
    const int P = (k >> 3) * 8 + xcd;         // [0,512)
    const int lt = P & 15, b = P >> 4;
    const int c0 = co_t * 64, l0 = lt * 256;

    // per-sample scale from pack_x partials (drained BEFORE staging so vmcnt
    // counts in the K-loop stay exact)
    float psum = partial[b * 64 + lane];
    for (int off = 32; off; off >>= 1) psum += __shfl_xor(psum, off, 64);
    const float sxb = psum * (1.0f / (float)((size_t)Cn * Ln));

    const char* zpad = (const char*)zpadf;
    const char* wqb = wq4;

    // staging sources (ko = kt*32 bytes added per K-step); LDS linear.
    const char* sA0;  // slot tid
    const char* sA1;  // slot 256+tid (tid<128), tap 2
    {
        int s = tid;
        sA0 = wqb + (size_t)(s >> 7) * Cn * 256 + (size_t)(c0 + ((s >> 1) & 63)) * 256 + (s & 1) * 16;
        s = 256 + (tid & 127);
        sA1 = wqb + (size_t)(s >> 7) * Cn * 256 + (size_t)(c0 + ((s >> 1) & 63)) * 256 + (s & 1) * 16;
    }
    const char* sB0;
    const char* sB1;
    const char* sB2;
    {
        int s = tid;
        int row = s >> 1, l = l0 - 1 + row;
        sB0 = (l >= 0 && l < Ln) ? xs4 + ((size_t)b * Ln + l) * 256 + (s & 1) * 16 : zpad;
        s = 256 + tid; row = s >> 1; l = l0 - 1 + row;
        sB1 = (l >= 0 && l < Ln) ? xs4 + ((size_t)b * Ln + l) * 256 + (s & 1) * 16 : zpad;
        s = 512 + (lane & 3); row = s >> 1; l = l0 - 1 + row;
        sB2 = (l >= 0 && l < Ln) ? xs4 + ((size_t)b * Ln + l) * 256 + (s & 1) * 16 : zpad;
    }

    // fragment LDS offsets: A row = m*32+cl (co), byte kh*16; B row = wc*64+n*32+cl+tap
    int aoff[2];
#pragma unroll
    for (int m = 0; m < 2; ++m) aoff[m] = (m * 32 + cl) * 32 + kh * 16;
    int boff[2][3];
#pragma unroll
    for (int n = 0; n < 2; ++n)
#pragma unroll
        for (int tap = 0; tap < 3; ++tap)
            boff[n][tap] = (wc * 64 + n * 32 + cl + tap) * 32 + kh * 16;

    f32x16 acc[2][2] = {};

    auto stage = [&](int kt, int tb) {
        char* base = (char*)lds + tb * 14400;
        const int ko = kt * 32;
        gload_lds16(sA0 + ko, base + tid * 16);
        if (wid < 2) gload_lds16(sA1 + ko, base + (256 + tid) * 16);   // tid<128
        char* bb = base + 6144;
        gload_lds16(sB0 + ko, bb + tid * 16);
        gload_lds16(sB1 + ko, bb + (256 + tid) * 16);
        if (wid == 0) {
            if (lane < 4) gload_lds16(sB2 + ko, bb + (512 + lane) * 16);
        }
    };
    // per-wave loads per stage: w0=5, w1=4, w2/3=3

    auto compute = [&](int tb) {
        const char* A = (const char*)lds + tb * 14400;
        const char* Bt = A + 6144;
#pragma unroll
        for (int tap = 0; tap < 3; ++tap) {
            i32x8 av[2], bv[2];
#pragma unroll
            for (int m = 0; m < 2; ++m) {
                const i32x4 t4 = *(const i32x4*)(A + tap * 2048 + aoff[m]);
                av[m] = i32x8{t4[0], t4[1], t4[2], t4[3], 0, 0, 0, 0};
            }
#pragma unroll
            for (int n = 0; n < 2; ++n) {
                const i32x4 t4 = *(const i32x4*)(Bt + boff[n][tap]);
                bv[n] = i32x8{t4[0], t4[1], t4[2], t4[3], 0, 0, 0, 0};
            }
            __builtin_amdgcn_s_setprio(1);
#pragma unroll
            for (int m = 0; m < 2; ++m)
#pragma unroll
                for (int n = 0; n < 2; ++n)
                    acc[m][n] = __builtin_amdgcn_mfma_scale_f32_32x32x64_f8f6f4(
                        av[m], bv[n], acc[m][n], 4 /*fp4 A*/, 4 /*fp4 B*/,
                        0, 0x7F7F7F7F, 0, 0x7F7F7F7F);   // e8m0 scales = 1.0
            __builtin_amdgcn_s_setprio(0);
        }
    };

    // depth-2 prefetch pipeline over 3 LDS buffers
    stage(0, 0);
    stage(1, 1);
#pragma unroll
    for (int kt = 0; kt < 8; ++kt) {
        const int buf = kt % 3;
        if (kt < 6) {
            stage(kt + 2, (kt + 2) % 3);      // two tiles in flight
            asm volatile("" ::: "memory");
            if (wid == 0)      asm volatile("s_waitcnt vmcnt(10)" ::: "memory");
            else if (wid == 1) asm volatile("s_waitcnt vmcnt(8)" ::: "memory");
            else               asm volatile("s_waitcnt vmcnt(6)" ::: "memory");
        } else if (kt == 6) {
            if (wid == 0)      asm volatile("s_waitcnt vmcnt(5)" ::: "memory");
            else if (wid == 1) asm volatile("s_waitcnt vmcnt(4)" ::: "memory");
            else               asm volatile("s_waitcnt vmcnt(3)" ::: "memory");
        } else {
            asm volatile("s_waitcnt vmcnt(0)" ::: "memory");
        }
        __builtin_amdgcn_s_barrier();         // buf fully staged for all waves
        compute(buf);
        asm volatile("" ::: "memory");
        __builtin_amdgcn_s_barrier();         // all waves done reading buf
    }

    // epilogue. 32x32 D: col=lane&31 (l), row=(reg&3)+8*(reg>>2)+4*(lane>>5) (co)
    // nontemporal: out is never re-read; keep xs4/wq4 resident in L2.
#pragma unroll
    for (int m = 0; m < 2; ++m)
#pragma unroll
        for (int n = 0; n < 2; ++n) {
            const int l = l0 + wc * 64 + n * 32 + cl;
#pragma unroll
            for (int g = 0; g < 4; ++g) {
                const int cob = c0 + m * 32 + g * 8 + kh * 4;
                const float4 swv = *(const float4*)(sw + cob);
                float* po = out + ((size_t)b * Cn + cob) * Ln + l;
                __builtin_nontemporal_store(acc[m][n][g * 4 + 0] * (sxb * swv.x), po);
                __builtin_nontemporal_store(acc[m][n][g * 4 + 1] * (sxb * swv.y), po + (size_t)Ln);
                __builtin_nontemporal_store(acc[m][n][g * 4 + 2] * (sxb * swv.z), po + (size_t)2 * Ln);
                __builtin_nontemporal_store(acc[m][n][g * 4 + 3] * (sxb * swv.w), po + (size_t)3 * Ln);
            }
        }
}

// ===================== fallback popcount path (round-1, passing) =====================
__global__ __launch_bounds__(64) void pack_w_kernel(const float* __restrict__ w,
                                                    u64* __restrict__ wp,
                                                    float* __restrict__ sw) {
    const int co = blockIdx.x;
    const int lane = threadIdx.x;
    const float* wrow = w + (size_t)co * Cn * 3;
    float asum = 0.0f;
    for (int wi = 0; wi < Wn; ++wi) {
        const int ci = wi * 64 + lane;
#pragma unroll
        for (int k = 0; k < 3; ++k) {
            const float v = wrow[ci * 3 + k];
            asum += fabsf(v);
            const u64 m = __ballot(v > 0.0f);
            if (lane == 0) wp[(co * 3 + k) * Wn + wi] = m;
        }
    }
    for (int off = 32; off; off >>= 1) asum += __shfl_xor(asum, off, 64);
    if (lane == 0) sw[co] = asum * (1.0f / (float)(Cn * 3));
}

__global__ __launch_bounds__(256) void pack_x_kernel(const float* __restrict__ x,
                                                     u64* __restrict__ xp,
                                                     float* __restrict__ partial) {
    const int b = blockIdx.z, wi = blockIdx.y;
    const int l = blockIdx.x * 256 + threadIdx.x;
    const float* xb = x + ((size_t)b * Cn + wi * 64) * Ln + l;
    u64 word = 0;
    float asum = 0.0f;
#pragma unroll 8
    for (int c = 0; c < 64; ++c) {
        const float v = xb[(size_t)c * Ln];
        asum += fabsf(v);
        word |= (u64)(v > 0.0f) << c;
    }
    xp[((size_t)b * Wn + wi) * Ln + l] = word;
    for (int off = 32; off; off >>= 1) asum += __shfl_xor(asum, off, 64);
    __shared__ float red[4];
    const int wave = threadIdx.x >> 6, lane = threadIdx.x & 63;
    if (lane == 0) red[wave] = asum;
    __syncthreads();
    if (threadIdx.x == 0)
        partial[b * 128 + wi * 16 + blockIdx.x] = red[0] + red[1] + red[2] + red[3];
}

__global__ __launch_bounds__(128) void finalize_sx_kernel(const float* __restrict__ partial,
                                                          float* __restrict__ sx) {
    const int b = blockIdx.x;
    float v = partial[b * 128 + threadIdx.x];
    for (int off = 32; off; off >>= 1) v += __shfl_xor(v, off, 64);
    __shared__ float red[2];
    if ((threadIdx.x & 63) == 0) red[threadIdx.x >> 6] = v;
    __syncthreads();
    if (threadIdx.x == 0) sx[b] = (red[0] + red[1]) * (1.0f / (float)((size_t)Cn * Ln));
}

__global__ __launch_bounds__(256) void conv_kernel(const u64* __restrict__ xp,
                                                   const u64* __restrict__ wp,
                                                   const float* __restrict__ sw,
                                                   const float* __restrict__ sx,
                                                   float* __restrict__ out) {
    __shared__ u64 wq[64 * 24];
    __shared__ float sws[64];
    const int b = blockIdx.z;
    const int c0 = blockIdx.y * 64;
    const int l0 = blockIdx.x * 64;
    for (int i = threadIdx.x; i < 64 * 24; i += 256) wq[i] = wp[(size_t)c0 * 24 + i];
    if (threadIdx.x < 64) sws[threadIdx.x] = sw[c0 + threadIdx.x];
    __syncthreads();
    const int lane = threadIdx.x & 63;
    const int wv = threadIdx.x >> 6;
    const int l = l0 + lane;
    const bool v0 = (l >= 1);
    const bool v2 = (l < Ln - 1);
    const int lmi = v0 ? l - 1 : l;
    const int lp = v2 ? l + 1 : l;
    const u64* xpb = xp + (size_t)b * Wn * Ln;
    u64 xq0[8], xq1[8], xq2[8];
#pragma unroll
    for (int wi = 0; wi < 8; ++wi) {
        const u64* p = xpb + (size_t)wi * Ln;
        xq0[wi] = p[lmi]; xq1[wi] = p[l]; xq2[wi] = p[lp];
    }
    const float sxb = sx[b];
    const size_t obase = ((size_t)b * Cn + c0 + wv * 16) * Ln + l;
#pragma unroll 2
    for (int ci = 0; ci < 16; ++ci) {
        const int col = wv * 16 + ci;
        const u64* wr = &wq[col * 24];
        int n0 = 0, n1 = 0, n2 = 0;
#pragma unroll
        for (int wi = 0; wi < 8; ++wi) {
            n0 += __popcll(xq0[wi] ^ wr[0 * 8 + wi]);
            n1 += __popcll(xq1[wi] ^ wr[1 * 8 + wi]);
            n2 += __popcll(xq2[wi] ^ wr[2 * 8 + wi]);
        }
        int s = 512 - 2 * n1;
        s += v0 ? (512 - 2 * n0) : 0;
        s += v2 ? (512 - 2 * n2) : 0;
        out[obase + (size_t)ci * Ln] = sxb * sws[col] * (float)s;
    }
}

// ============================ launch ============================
extern "C" void kernel_launch(void* const* d_in, const int* in_sizes, int n_in,
                              void* d_out, int out_size, void* d_ws, size_t ws_size,
                              hipStream_t stream) {
    const float* x = (const float*)d_in[0];   // [32, 512, 4096] f32
    const float* w = (const float*)d_in[1];   // [512, 512, 3]  f32
    float* out = (float*)d_out;               // [32, 512, 4096] f32
    char* ws = (char*)d_ws;

    // fp4 path workspace: xs4 33554432 | wq4 393216 | zpad 512 | sw 2048 | sx 128 | partial 8192
    const size_t NEED = 33958528;
    if (ws_size >= NEED) {
        char* xs4 = ws;                              // [b][l][ci/2] fp4
        u32* wq4 = (u32*)(ws + 33554432);            // [tap][co][ci/2] fp4
        float* zpad = (float*)(ws + 33947648);       // 512 B zeros
        float* sw = (float*)(ws + 33948160);
        float* partial = (float*)(ws + 33950336);

        pack_w_fp4_kernel<<<dim3(Cn), dim3(64), 0, stream>>>(w, wq4, sw, zpad);
        pack_x_fp4_kernel<<<dim3(Ln / 64, Bn), dim3(256), 0, stream>>>(x, xs4, partial);
        xgemm_fp4_kernel<<<dim3(4096), dim3(256), 0, stream>>>(xs4, (const char*)wq4, sw, partial, zpad, out);
    } else {
        const size_t xp_bytes = (size_t)Bn * Wn * Ln * sizeof(u64);
        const size_t wp_bytes = (size_t)Cn * 3 * Wn * sizeof(u64);
        u64* xp = (u64*)ws;
        u64* wp = (u64*)(ws + xp_bytes);
        float* sw = (float*)(ws + xp_bytes + wp_bytes);
        float* partial = sw + Cn;
        float* sx = partial + Bn * 128;

        pack_w_kernel<<<dim3(Cn), dim3(64), 0, stream>>>(w, wp, sw);
        pack_x_kernel<<<dim3(Ln / 256, Wn, Bn), dim3(256), 0, stream>>>(x, xp, partial);
        finalize_sx_kernel<<<dim3(Bn), dim3(128), 0, stream>>>(partial, sx);
        conv_kernel<<<dim3(Ln / 64, Cn / 64, Bn), dim3(256), 0, stream>>>(xp, wp, sw, sx, out);
    }
}